// Round 2
// baseline (1603.154 us; speedup 1.0000x reference)
//
#include <hip/hip_runtime.h>
#include <stdint.h>

#define BATCH 8192
#define DIM   2048
#define HPAD  5376
#define HSRC  5324

typedef __bf16 bf16x8 __attribute__((ext_vector_type(8)));
typedef float  f32x4  __attribute__((ext_vector_type(4)));
typedef unsigned short u16x4 __attribute__((ext_vector_type(4)));

static __device__ __forceinline__ unsigned short f2bf(float f) {
  unsigned u = __builtin_bit_cast(unsigned, f);
  unsigned r = (u + 0x7FFFu + ((u >> 16) & 1u)) >> 16;
  return (unsigned short)r;
}
static __device__ __forceinline__ float bf2f(unsigned short s) {
  return __builtin_bit_cast(float, ((unsigned)s) << 16);
}

// async global->LDS, 16B per lane. LDS dest must be wave-uniform base + lane*16.
static __device__ __forceinline__ void gload_lds16(const void* g, void* l) {
  __builtin_amdgcn_global_load_lds(
      (__attribute__((address_space(1))) void*)(uintptr_t)g,
      (__attribute__((address_space(3))) void*)(uintptr_t)l, 16, 0, 0);
}

// ---------------------------------------------------------------------------
// GEMM: C[M,N] = A[M,K] * B[N,K]^T (+bias), bf16 in, f32 accum.
// 128x128 tile, BK=64, 256 threads (2x2 waves, each 64x64 = 4x4 frags 16x16).
// Epilogues:
//  1: bfout[row*bf_ld+col] = bf16(val)                        (v, u1)
//  3: fout[idx]  = (fin0+fin1)*0.7071 + val                   (h2)
//  4: u=bf16(bfin[idx]); bfout[idx] = bf16(silu(u)*val)       (g, in-place ok)
//  5: bfout[row*bf_ld+col] = bf16(fin0[idx] + val)            (cand -> concat)
//  6: z=sigmoid(val); c=bf2f(bfin[row*bf_ld+col]);
//     fout[idx] = z*c + (1-z)*fin1[idx]                       (final mix)
// ---------------------------------------------------------------------------
template<int EPI>
__global__ __launch_bounds__(256, 2)
void gemm_bf16(const unsigned short* __restrict__ A,
               const unsigned short* __restrict__ B,
               const int N, const int K,
               const float* __restrict__ bias,
               const float* __restrict__ fin0,
               const float* __restrict__ fin1,
               const unsigned short* bfin,   // may alias bfout (EPI 4)
               float* __restrict__ fout,
               unsigned short* bfout,
               const int bf_ld)
{
  __shared__ __attribute__((aligned(16))) unsigned short As[128 * 64];
  __shared__ __attribute__((aligned(16))) unsigned short Bs[128 * 64];

  const int tid  = threadIdx.x;
  const int lane = tid & 63;
  const int wid  = tid >> 6;
  const int bn0  = blockIdx.x * 128;
  const int bm0  = blockIdx.y * 128;
  const int wr   = (wid >> 1) * 64;
  const int wc   = (wid & 1) * 64;
  const int fm   = lane & 15;
  const int fk   = (lane >> 4) * 8;

  f32x4 acc[4][4];
#pragma unroll
  for (int m = 0; m < 4; ++m)
#pragma unroll
    for (int n = 0; n < 4; ++n)
      acc[m][n] = f32x4{0.f, 0.f, 0.f, 0.f};

  for (int kt = 0; kt < K; kt += 64) {
#pragma unroll
    for (int i = 0; i < 4; ++i) {
      const int s = i * 256 + tid;
      const int r = s >> 3;
      const int c = (s & 7) << 3;
      gload_lds16(A + (size_t)(bm0 + r) * K + kt + c, &As[s * 8]);
      gload_lds16(B + (size_t)(bn0 + r) * K + kt + c, &Bs[s * 8]);
    }
    __syncthreads();  // drains vmcnt for global_load_lds + barrier
#pragma unroll
    for (int kk = 0; kk < 2; ++kk) {
      bf16x8 a[4], b[4];
#pragma unroll
      for (int m = 0; m < 4; ++m)
        a[m] = *(const bf16x8*)&As[(wr + m * 16 + fm) * 64 + kk * 32 + fk];
#pragma unroll
      for (int n = 0; n < 4; ++n)
        b[n] = *(const bf16x8*)&Bs[(wc + n * 16 + fm) * 64 + kk * 32 + fk];
#pragma unroll
      for (int m = 0; m < 4; ++m)
#pragma unroll
        for (int n = 0; n < 4; ++n)
          acc[m][n] = __builtin_amdgcn_mfma_f32_16x16x32_bf16(a[m], b[n], acc[m][n], 0, 0, 0);
    }
    __syncthreads();
  }

  const int row0 = bm0 + wr + (lane >> 4) * 4;
  const int col0 = bn0 + wc + fm;
#pragma unroll
  for (int m = 0; m < 4; ++m) {
#pragma unroll
    for (int n = 0; n < 4; ++n) {
      const int col = col0 + n * 16;
      const float bv = bias ? bias[col] : 0.f;
#pragma unroll
      for (int r = 0; r < 4; ++r) {
        const int row = row0 + m * 16 + r;
        float val = acc[m][n][r] + bv;
        const size_t idx = (size_t)row * N + col;
        if constexpr (EPI == 1) {
          bfout[(size_t)row * bf_ld + col] = f2bf(val);
        } else if constexpr (EPI == 3) {
          fout[idx] = (fin0[idx] + fin1[idx]) * 0.7071f + val;
        } else if constexpr (EPI == 4) {
          const float u = bf2f(bfin[idx]);
          const float s = u / (1.f + __expf(-u));
          bfout[idx] = f2bf(s * val);
        } else if constexpr (EPI == 5) {
          bfout[(size_t)row * bf_ld + col] = f2bf(fin0[idx] + val);
        } else if constexpr (EPI == 6) {
          const float z = 1.f / (1.f + __expf(-val));
          const float c = bf2f(bfin[(size_t)row * bf_ld + col]);
          fout[idx] = z * c + (1.f - z) * fin1[idx];
        }
      }
    }
  }
}

// ---------------------------------------------------------------------------
// RMSNorm (f32 exact). PREP: input is (in0+in1)*0.7071. Out: bf16 normed row.
// ---------------------------------------------------------------------------
template<bool PREP>
__global__ __launch_bounds__(256)
void norm_kernel(const float* __restrict__ in0, const float* __restrict__ in1,
                 const float* __restrict__ g, unsigned short* __restrict__ n_out)
{
  const int row = blockIdx.x;
  const int t   = threadIdx.x;
  const size_t base = (size_t)row * DIM;

  const float4* p0 = (const float4*)(in0 + base);
  float4 a0 = p0[t];
  float4 a1 = p0[t + 256];
  if constexpr (PREP) {
    const float4* p1 = (const float4*)(in1 + base);
    float4 s0 = p1[t];
    float4 s1 = p1[t + 256];
    a0.x = (a0.x + s0.x) * 0.7071f; a0.y = (a0.y + s0.y) * 0.7071f;
    a0.z = (a0.z + s0.z) * 0.7071f; a0.w = (a0.w + s0.w) * 0.7071f;
    a1.x = (a1.x + s1.x) * 0.7071f; a1.y = (a1.y + s1.y) * 0.7071f;
    a1.z = (a1.z + s1.z) * 0.7071f; a1.w = (a1.w + s1.w) * 0.7071f;
  }

  float ss = a0.x * a0.x + a0.y * a0.y + a0.z * a0.z + a0.w * a0.w
           + a1.x * a1.x + a1.y * a1.y + a1.z * a1.z + a1.w * a1.w;
#pragma unroll
  for (int off = 32; off > 0; off >>= 1) ss += __shfl_xor(ss, off, 64);
  __shared__ float red[4];
  if ((t & 63) == 0) red[t >> 6] = ss;
  __syncthreads();
  const float tot = red[0] + red[1] + red[2] + red[3];
  const float scale = 0.022097086912079608f / fmaxf(sqrtf(tot), 1e-6f);

  const float4 g0 = ((const float4*)g)[t];
  const float4 g1 = ((const float4*)g)[t + 256];
  u16x4 o0, o1;
  o0.x = f2bf(a0.x * scale * g0.x); o0.y = f2bf(a0.y * scale * g0.y);
  o0.z = f2bf(a0.z * scale * g0.z); o0.w = f2bf(a0.w * scale * g0.w);
  o1.x = f2bf(a1.x * scale * g1.x); o1.y = f2bf(a1.y * scale * g1.y);
  o1.z = f2bf(a1.z * scale * g1.z); o1.w = f2bf(a1.w * scale * g1.w);
  *(u16x4*)&n_out[base + 4 * t]        = o0;
  *(u16x4*)&n_out[base + 1024 + 4 * t] = o1;
}

// f32 -> bf16 weight convert, zero-padded to dst_cols (and rows via guard).
__global__ __launch_bounds__(256)
void convert_pad(const float* __restrict__ src, unsigned short* __restrict__ dst,
                 const int src_rows, const int src_cols, const int dst_cols,
                 const int total4)
{
  const int i = blockIdx.x * 256 + threadIdx.x;
  if (i >= total4) return;
  const int e = i * 4;
  const int r = e / dst_cols;
  const int c = e - r * dst_cols;
  u16x4 o;
  if (r < src_rows && c < src_cols) {
    const float4 v = *(const float4*)(src + (size_t)r * src_cols + c);
    o.x = f2bf(v.x); o.y = f2bf(v.y); o.z = f2bf(v.z); o.w = f2bf(v.w);
  } else {
    o.x = 0; o.y = 0; o.z = 0; o.w = 0;
  }
  *(u16x4*)(dst + e) = o;
}

// state (f32, [B, DIM]) -> bf16 into concat buffer cols [DIM, 2*DIM)
__global__ __launch_bounds__(256)
void state_to_cc(const float* __restrict__ st, unsigned short* __restrict__ cc)
{
  const int i = blockIdx.x * 256 + threadIdx.x;  // over BATCH*DIM/4
  const int e = i * 4;
  const int r = e >> 11;          // /DIM
  const int c = e & (DIM - 1);
  const float4 v = *(const float4*)(st + e);
  u16x4 o;
  o.x = f2bf(v.x); o.y = f2bf(v.y); o.z = f2bf(v.z); o.w = f2bf(v.w);
  *(u16x4*)&cc[(size_t)r * (2 * DIM) + DIM + c] = o;
}

extern "C" void kernel_launch(void* const* d_in, const int* in_sizes, int n_in,
                              void* d_out, int out_size, void* d_ws, size_t ws_size,
                              hipStream_t stream)
{
  const float* x   = (const float*)d_in[0];
  const float* st  = (const float*)d_in[1];
  const float* g1  = (const float*)d_in[2];
  const float* g2  = (const float*)d_in[3];
  const float* ipw = (const float*)d_in[4];
  const float* ipb = (const float*)d_in[5];
  const float* opw = (const float*)d_in[6];
  const float* opb = (const float*)d_in[7];
  const float* w1  = (const float*)d_in[8];
  const float* w2  = (const float*)d_in[9];
  const float* w3  = (const float*)d_in[10];
  const float* gw  = (const float*)d_in[11];
  const float* gb  = (const float*)d_in[12];

  char* p = (char*)d_ws;
  auto alloc = [&](size_t bytes) { void* r = (void*)p; p += bytes; return r; };

  // 233 MiB total — stay well under any plausible ws_size.
  unsigned short* wA   = (unsigned short*)alloc((size_t)HPAD * DIM * 2);   // 22 MiB, reused for every weight
  unsigned short* hn   = (unsigned short*)alloc((size_t)BATCH * DIM * 2);  // 32 MiB (later: cc lower half)
  unsigned short* v    = (unsigned short*)alloc((size_t)BATCH * DIM * 2);  // 32 MiB (later: cc upper half)
  float*          h2   = (float*)alloc((size_t)BATCH * DIM * 4);           // 64 MiB
  unsigned short* gbuf = (unsigned short*)alloc((size_t)BATCH * HPAD * 2); // 84 MiB (u1 then g, in-place)
  unsigned short* cc   = hn;  // [BATCH, 2*DIM] bf16 overlays hn+v (both dead by then)
  unsigned short* hn2  = hn;  // hn dead after GEMM1

  const dim3 blk(256);
  const int t4_dd = DIM * DIM / 4;
  const int t4_hd = HPAD * DIM / 4;
  const int t4_dh = DIM * HPAD / 4;
  const int t4_dg = DIM * 2 * DIM / 4;

  // hn = rmsnorm((x+state)*0.7071, g1)
  norm_kernel<true><<<BATCH, 256, 0, stream>>>(x, st, g1, hn);

  // v = hn @ Wv^T + b_v          (Wv = rows [2*DIM, 3*DIM) of in_proj_w)
  convert_pad<<<(t4_dd + 255) / 256, 256, 0, stream>>>(ipw + (size_t)2 * DIM * DIM, wA, DIM, DIM, DIM, t4_dd);
  gemm_bf16<1><<<dim3(16, 64), blk, 0, stream>>>(hn, wA, DIM, DIM, ipb + 2 * DIM,
      nullptr, nullptr, nullptr, nullptr, v, DIM);

  // h2 = (x+state)*0.7071 + (v @ Wo^T + b_o)
  convert_pad<<<(t4_dd + 255) / 256, 256, 0, stream>>>(opw, wA, DIM, DIM, DIM, t4_dd);
  gemm_bf16<3><<<dim3(16, 64), blk, 0, stream>>>(v, wA, DIM, DIM, opb,
      x, st, nullptr, h2, nullptr, 0);

  // hn2 = rmsnorm(h2, g2)
  norm_kernel<false><<<BATCH, 256, 0, stream>>>(h2, nullptr, g2, hn2);

  // u1 = hn2 @ w1^T   (into gbuf, HPAD-padded)
  convert_pad<<<(t4_hd + 255) / 256, 256, 0, stream>>>(w1, wA, HSRC, DIM, DIM, t4_hd);
  gemm_bf16<1><<<dim3(HPAD / 128, 64), blk, 0, stream>>>(hn2, wA, HPAD, DIM, nullptr,
      nullptr, nullptr, nullptr, nullptr, gbuf, HPAD);

  // g = silu(u1) * (hn2 @ w2^T)   (in-place on gbuf)
  convert_pad<<<(t4_hd + 255) / 256, 256, 0, stream>>>(w2, wA, HSRC, DIM, DIM, t4_hd);
  gemm_bf16<4><<<dim3(HPAD / 128, 64), blk, 0, stream>>>(hn2, wA, HPAD, DIM, nullptr,
      nullptr, nullptr, gbuf, nullptr, gbuf, HPAD);

  // concat upper half: cc[:, DIM:2*DIM] = bf16(state)   (hn/v dead now)
  state_to_cc<<<(BATCH * DIM / 4) / 256, 256, 0, stream>>>(st, cc);

  // cand = h2 + g @ w3^T  ->  cc[:, 0:DIM] = bf16(cand)
  convert_pad<<<(t4_dh + 255) / 256, 256, 0, stream>>>(w3, wA, DIM, HSRC, HPAD, t4_dh);
  gemm_bf16<5><<<dim3(16, 64), blk, 0, stream>>>(gbuf, wA, DIM, HPAD, nullptr,
      h2, nullptr, nullptr, nullptr, cc, 2 * DIM);

  // out = z*cand + (1-z)*state,  z = sigmoid(cc @ gate_w^T + gate_b)
  convert_pad<<<(t4_dg + 255) / 256, 256, 0, stream>>>(gw, wA, DIM, 2 * DIM, 2 * DIM, t4_dg);
  gemm_bf16<6><<<dim3(16, 64), blk, 0, stream>>>(cc, wA, DIM, 2 * DIM, gb,
      nullptr, st, cc, (float*)d_out, nullptr, 2 * DIM);
}

// Round 3
// 1278.321 us; speedup vs baseline: 1.2541x; 1.2541x over previous
//
#include <hip/hip_runtime.h>
#include <stdint.h>

#define BATCH 8192
#define DIM   2048
#define HPAD  5376
#define HSRC  5324

typedef __bf16 bf16x8 __attribute__((ext_vector_type(8)));
typedef float  f32x4  __attribute__((ext_vector_type(4)));
typedef unsigned short u16x4 __attribute__((ext_vector_type(4)));

static __device__ __forceinline__ unsigned short f2bf(float f) {
  unsigned u = __builtin_bit_cast(unsigned, f);
  unsigned r = (u + 0x7FFFu + ((u >> 16) & 1u)) >> 16;
  return (unsigned short)r;
}
static __device__ __forceinline__ float bf2f(unsigned short s) {
  return __builtin_bit_cast(float, ((unsigned)s) << 16);
}

// async global->LDS, 16B per lane. LDS dest must be wave-uniform base + lane*16.
static __device__ __forceinline__ void gload_lds16(const void* g, void* l) {
  __builtin_amdgcn_global_load_lds(
      (__attribute__((address_space(1))) void*)(uintptr_t)g,
      (__attribute__((address_space(3))) void*)(uintptr_t)l, 16, 0, 0);
}

// ---------------------------------------------------------------------------
// 256x256-tile 8-phase GEMM (T2 swizzle + T3/T4 counted-vmcnt + T5 setprio).
// C[M,N] = A[M,K] * B[N,K]^T (+bias). bf16 in, f32 accum. M=8192 fixed.
// 512 threads = 8 waves (2M x 4N); per-wave C = 128x64 = 8rf x 4cf frags.
// LDS 128KiB: buf{0,1} x {A: 256x64 (32KB), B: 256x64 (32KB)} bf16.
// LDS layout: elem (row, kbyte) at region + row*128 + (kbyte ^ ((row&7)<<4)).
// Stage: linear LDS dest (gload_lds), inverse-swizzled GLOBAL source.
// Phase p of tile t: {ds_read A rf(2p,2p+1) [+ B frags at p1]; stage; [vmcnt];
//   s_barrier; lgkmcnt(0); setprio(1); 16 MFMA; setprio(0); s_barrier}.
// Stage schedule per iter (tiles t in buf0, t+1 in buf1):
//   p1: A(t+1)->buf1 | p2: B0(t+2)->buf0 | p3: B1(t+2) | p4: vmcnt(4)
//   p5: A(t+2)->buf0 | p6: B0(t+3)->buf1 | p7: B1(t+3) | p8: vmcnt(4)
// Every stage targets a region last ds_read >=1 barrier earlier; vmcnt(4)
// guarantees everything except the newest 2 half-tiles has landed.
// ---------------------------------------------------------------------------
#define MFMA16(RF0)                                                                                  \
    acc[RF0][0]   = __builtin_amdgcn_mfma_f32_16x16x32_bf16(a00, bfr[0][0], acc[RF0][0], 0, 0, 0);   \
    acc[RF0][0]   = __builtin_amdgcn_mfma_f32_16x16x32_bf16(a01, bfr[0][1], acc[RF0][0], 0, 0, 0);   \
    acc[RF0][1]   = __builtin_amdgcn_mfma_f32_16x16x32_bf16(a00, bfr[1][0], acc[RF0][1], 0, 0, 0);   \
    acc[RF0][1]   = __builtin_amdgcn_mfma_f32_16x16x32_bf16(a01, bfr[1][1], acc[RF0][1], 0, 0, 0);   \
    acc[RF0][2]   = __builtin_amdgcn_mfma_f32_16x16x32_bf16(a00, bfr[2][0], acc[RF0][2], 0, 0, 0);   \
    acc[RF0][2]   = __builtin_amdgcn_mfma_f32_16x16x32_bf16(a01, bfr[2][1], acc[RF0][2], 0, 0, 0);   \
    acc[RF0][3]   = __builtin_amdgcn_mfma_f32_16x16x32_bf16(a00, bfr[3][0], acc[RF0][3], 0, 0, 0);   \
    acc[RF0][3]   = __builtin_amdgcn_mfma_f32_16x16x32_bf16(a01, bfr[3][1], acc[RF0][3], 0, 0, 0);   \
    acc[RF0+1][0] = __builtin_amdgcn_mfma_f32_16x16x32_bf16(a10, bfr[0][0], acc[RF0+1][0], 0, 0, 0); \
    acc[RF0+1][0] = __builtin_amdgcn_mfma_f32_16x16x32_bf16(a11, bfr[0][1], acc[RF0+1][0], 0, 0, 0); \
    acc[RF0+1][1] = __builtin_amdgcn_mfma_f32_16x16x32_bf16(a10, bfr[1][0], acc[RF0+1][1], 0, 0, 0); \
    acc[RF0+1][1] = __builtin_amdgcn_mfma_f32_16x16x32_bf16(a11, bfr[1][1], acc[RF0+1][1], 0, 0, 0); \
    acc[RF0+1][2] = __builtin_amdgcn_mfma_f32_16x16x32_bf16(a10, bfr[2][0], acc[RF0+1][2], 0, 0, 0); \
    acc[RF0+1][2] = __builtin_amdgcn_mfma_f32_16x16x32_bf16(a11, bfr[2][1], acc[RF0+1][2], 0, 0, 0); \
    acc[RF0+1][3] = __builtin_amdgcn_mfma_f32_16x16x32_bf16(a10, bfr[3][0], acc[RF0+1][3], 0, 0, 0); \
    acc[RF0+1][3] = __builtin_amdgcn_mfma_f32_16x16x32_bf16(a11, bfr[3][1], acc[RF0+1][3], 0, 0, 0);

#define PHASE(BUFOFF, RF0, READB, STAGE_STMT, VM_STMT)                            \
  {                                                                               \
    if (READB) {                                                                  \
      bfr[0][0] = *(const bf16x8*)(lds + (BUFOFF) + rowB + 0 * 2048 + kof0);      \
      bfr[0][1] = *(const bf16x8*)(lds + (BUFOFF) + rowB + 0 * 2048 + kof1);      \
      bfr[1][0] = *(const bf16x8*)(lds + (BUFOFF) + rowB + 1 * 2048 + kof0);      \
      bfr[1][1] = *(const bf16x8*)(lds + (BUFOFF) + rowB + 1 * 2048 + kof1);      \
      bfr[2][0] = *(const bf16x8*)(lds + (BUFOFF) + rowB + 2 * 2048 + kof0);      \
      bfr[2][1] = *(const bf16x8*)(lds + (BUFOFF) + rowB + 2 * 2048 + kof1);      \
      bfr[3][0] = *(const bf16x8*)(lds + (BUFOFF) + rowB + 3 * 2048 + kof0);      \
      bfr[3][1] = *(const bf16x8*)(lds + (BUFOFF) + rowB + 3 * 2048 + kof1);      \
    }                                                                             \
    bf16x8 a00 = *(const bf16x8*)(lds + (BUFOFF) + rowA + (RF0) * 2048 + kof0);   \
    bf16x8 a01 = *(const bf16x8*)(lds + (BUFOFF) + rowA + (RF0) * 2048 + kof1);   \
    bf16x8 a10 = *(const bf16x8*)(lds + (BUFOFF) + rowA + (RF0+1) * 2048 + kof0); \
    bf16x8 a11 = *(const bf16x8*)(lds + (BUFOFF) + rowA + (RF0+1) * 2048 + kof1); \
    STAGE_STMT;                                                                   \
    VM_STMT;                                                                      \
    asm volatile("s_barrier" ::: "memory");                                       \
    asm volatile("s_waitcnt lgkmcnt(0)" ::: "memory");                            \
    __builtin_amdgcn_sched_barrier(0);                                            \
    __builtin_amdgcn_s_setprio(1);                                                \
    MFMA16(RF0)                                                                   \
    __builtin_amdgcn_s_setprio(0);                                                \
    asm volatile("s_barrier" ::: "memory");                                       \
  }

template<int EPI>
__global__ __launch_bounds__(512, 2)
void gemm256(const unsigned short* __restrict__ A,
             const unsigned short* __restrict__ B,
             const int N, const int K,
             const float* __restrict__ bias,
             const float* __restrict__ fin0,
             const float* __restrict__ fin1,
             const unsigned short* bfin,   // may alias bfout (EPI 4)
             float* __restrict__ fout,
             unsigned short* bfout,
             const int bf_ld)
{
  extern __shared__ char lds[];   // 131072 bytes
  const int tid  = threadIdx.x;
  const int lane = tid & 63;
  const int wid  = tid >> 6;
  const int wm   = wid >> 2;       // 0..1
  const int wn   = wid & 3;        // 0..3
  const int fm   = lane & 15;
  const int g    = lane >> 4;      // 0..3

  // XCD-bijective swizzle (all our grids are %8==0), then m-fastest mapping
  const int nwg = (N >> 8) * 32;
  int bid = blockIdx.x;
  bid = (bid & 7) * (nwg >> 3) + (bid >> 3);
  const int bm0 = (bid & 31) << 8;
  const int bn0 = (bid >> 5) << 8;

  const int NT = K >> 6;

  // ---- staging (linear LDS dest, inverse-swizzled global source) ----
  const int roff = tid >> 3;                         // row within 64-row chunk
  const int cel  = (((tid & 7) ^ (roff & 7)) << 3);  // k-elem offset (swizzled)
  auto stageA2 = [&](int t, int bufo) {              // both halves, 4 gloads
#pragma unroll
    for (int j = 0; j < 4; ++j)
      gload_lds16(A + (size_t)(bm0 + j * 64 + roff) * K + t * 64 + cel,
                  lds + bufo + j * 8192 + tid * 16);
  };
  auto stageBh = [&](int t, int bufo, int h) {       // one half, 2 gloads
#pragma unroll
    for (int j = 0; j < 2; ++j)
      gload_lds16(B + (size_t)(bn0 + h * 128 + j * 64 + roff) * K + t * 64 + cel,
                  lds + bufo + 32768 + h * 16384 + j * 8192 + tid * 16);
  };

  // ---- swizzled ds_read offsets ----
  const int swzb = (fm & 7) << 4;
  const int rowA = (wm * 128 + fm) * 128;
  const int rowB = 32768 + (wn * 64 + fm) * 128;
  const int kof0 = (g * 16) ^ swzb;
  const int kof1 = (64 + g * 16) ^ swzb;

  f32x4 acc[8][4];
#pragma unroll
  for (int i = 0; i < 8; ++i)
#pragma unroll
    for (int j = 0; j < 4; ++j)
      acc[i][j] = f32x4{0.f, 0.f, 0.f, 0.f};
  bf16x8 bfr[4][2];

  // ---- prologue: A(0),B(0) -> buf0; B(1) -> buf1 ----
  stageA2(0, 0);
  stageBh(0, 0, 0); stageBh(0, 0, 1);
  stageBh(1, 65536, 0); stageBh(1, 65536, 1);
  asm volatile("s_waitcnt vmcnt(4)" ::: "memory");   // A(0),B(0) landed
  asm volatile("s_barrier" ::: "memory");

  for (int t = 0; t < NT; t += 2) {
    // tile t from buf0
    PHASE(0, 0, true,  { stageA2(t + 1, 65536); }, {});
    PHASE(0, 2, false, { if (t + 2 < NT) stageBh(t + 2, 0, 0); }, {});
    PHASE(0, 4, false, { if (t + 2 < NT) stageBh(t + 2, 0, 1); }, {});
    PHASE(0, 6, false, {}, { asm volatile("s_waitcnt vmcnt(4)" ::: "memory"); });
    // tile t+1 from buf1
    PHASE(65536, 0, true,  { if (t + 2 < NT) stageA2(t + 2, 0); }, {});
    PHASE(65536, 2, false, { if (t + 3 < NT) stageBh(t + 3, 65536, 0); }, {});
    PHASE(65536, 4, false, { if (t + 3 < NT) stageBh(t + 3, 65536, 1); }, {});
    PHASE(65536, 6, false, {}, { asm volatile("s_waitcnt vmcnt(4)" ::: "memory"); });
  }

  // ---- epilogue ----
#pragma unroll
  for (int rf = 0; rf < 8; ++rf) {
#pragma unroll
    for (int cf = 0; cf < 4; ++cf) {
      const int col = bn0 + wn * 64 + cf * 16 + fm;
      const float bv = bias ? bias[col] : 0.f;
#pragma unroll
      for (int r = 0; r < 4; ++r) {
        const int row = bm0 + wm * 128 + rf * 16 + g * 4 + r;
        float val = acc[rf][cf][r] + bv;
        const size_t idx = (size_t)row * N + col;
        if constexpr (EPI == 1) {
          bfout[(size_t)row * bf_ld + col] = f2bf(val);
        } else if constexpr (EPI == 3) {
          fout[idx] = (fin0[idx] + fin1[idx]) * 0.7071f + val;
        } else if constexpr (EPI == 4) {
          const float u = bf2f(bfin[idx]);
          const float s = u / (1.f + __expf(-u));
          bfout[idx] = f2bf(s * val);
        } else if constexpr (EPI == 5) {
          bfout[(size_t)row * bf_ld + col] = f2bf(fin0[idx] + val);
        } else if constexpr (EPI == 6) {
          const float z = 1.f / (1.f + __expf(-val));
          const float c = bf2f(bfin[(size_t)row * bf_ld + col]);
          fout[idx] = z * c + (1.f - z) * fin1[idx];
        }
      }
    }
  }
}

// ---------------------------------------------------------------------------
// RMSNorm (f32 exact). PREP: input is (in0+in1)*0.7071. Out: bf16 normed row.
// ---------------------------------------------------------------------------
template<bool PREP>
__global__ __launch_bounds__(256)
void norm_kernel(const float* __restrict__ in0, const float* __restrict__ in1,
                 const float* __restrict__ g, unsigned short* __restrict__ n_out)
{
  const int row = blockIdx.x;
  const int t   = threadIdx.x;
  const size_t base = (size_t)row * DIM;

  const float4* p0 = (const float4*)(in0 + base);
  float4 a0 = p0[t];
  float4 a1 = p0[t + 256];
  if constexpr (PREP) {
    const float4* p1 = (const float4*)(in1 + base);
    float4 s0 = p1[t];
    float4 s1 = p1[t + 256];
    a0.x = (a0.x + s0.x) * 0.7071f; a0.y = (a0.y + s0.y) * 0.7071f;
    a0.z = (a0.z + s0.z) * 0.7071f; a0.w = (a0.w + s0.w) * 0.7071f;
    a1.x = (a1.x + s1.x) * 0.7071f; a1.y = (a1.y + s1.y) * 0.7071f;
    a1.z = (a1.z + s1.z) * 0.7071f; a1.w = (a1.w + s1.w) * 0.7071f;
  }

  float ss = a0.x * a0.x + a0.y * a0.y + a0.z * a0.z + a0.w * a0.w
           + a1.x * a1.x + a1.y * a1.y + a1.z * a1.z + a1.w * a1.w;
#pragma unroll
  for (int off = 32; off > 0; off >>= 1) ss += __shfl_xor(ss, off, 64);
  __shared__ float red[4];
  if ((t & 63) == 0) red[t >> 6] = ss;
  __syncthreads();
  const float tot = red[0] + red[1] + red[2] + red[3];
  const float scale = 0.022097086912079608f / fmaxf(sqrtf(tot), 1e-6f);

  const float4 g0 = ((const float4*)g)[t];
  const float4 g1 = ((const float4*)g)[t + 256];
  u16x4 o0, o1;
  o0.x = f2bf(a0.x * scale * g0.x); o0.y = f2bf(a0.y * scale * g0.y);
  o0.z = f2bf(a0.z * scale * g0.z); o0.w = f2bf(a0.w * scale * g0.w);
  o1.x = f2bf(a1.x * scale * g1.x); o1.y = f2bf(a1.y * scale * g1.y);
  o1.z = f2bf(a1.z * scale * g1.z); o1.w = f2bf(a1.w * scale * g1.w);
  *(u16x4*)&n_out[base + 4 * t]        = o0;
  *(u16x4*)&n_out[base + 1024 + 4 * t] = o1;
}

// f32 -> bf16 weight convert, zero-padded to dst_cols (and rows via guard).
__global__ __launch_bounds__(256)
void convert_pad(const float* __restrict__ src, unsigned short* __restrict__ dst,
                 const int src_rows, const int src_cols, const int dst_cols,
                 const int total4)
{
  const int i = blockIdx.x * 256 + threadIdx.x;
  if (i >= total4) return;
  const int e = i * 4;
  const int r = e / dst_cols;
  const int c = e - r * dst_cols;
  u16x4 o;
  if (r < src_rows && c < src_cols) {
    const float4 v = *(const float4*)(src + (size_t)r * src_cols + c);
    o.x = f2bf(v.x); o.y = f2bf(v.y); o.z = f2bf(v.z); o.w = f2bf(v.w);
  } else {
    o.x = 0; o.y = 0; o.z = 0; o.w = 0;
  }
  *(u16x4*)(dst + e) = o;
}

// state (f32, [B, DIM]) -> bf16 into concat buffer cols [DIM, 2*DIM)
__global__ __launch_bounds__(256)
void state_to_cc(const float* __restrict__ st, unsigned short* __restrict__ cc)
{
  const int i = blockIdx.x * 256 + threadIdx.x;  // over BATCH*DIM/4
  const int e = i * 4;
  const int r = e >> 11;          // /DIM
  const int c = e & (DIM - 1);
  const float4 v = *(const float4*)(st + e);
  u16x4 o;
  o.x = f2bf(v.x); o.y = f2bf(v.y); o.z = f2bf(v.z); o.w = f2bf(v.w);
  *(u16x4*)&cc[(size_t)r * (2 * DIM) + DIM + c] = o;
}

extern "C" void kernel_launch(void* const* d_in, const int* in_sizes, int n_in,
                              void* d_out, int out_size, void* d_ws, size_t ws_size,
                              hipStream_t stream)
{
  const float* x   = (const float*)d_in[0];
  const float* st  = (const float*)d_in[1];
  const float* g1  = (const float*)d_in[2];
  const float* g2  = (const float*)d_in[3];
  const float* ipw = (const float*)d_in[4];
  const float* ipb = (const float*)d_in[5];
  const float* opw = (const float*)d_in[6];
  const float* opb = (const float*)d_in[7];
  const float* w1  = (const float*)d_in[8];
  const float* w2  = (const float*)d_in[9];
  const float* w3  = (const float*)d_in[10];
  const float* gw  = (const float*)d_in[11];
  const float* gb  = (const float*)d_in[12];

  char* p = (char*)d_ws;
  auto alloc = [&](size_t bytes) { void* r = (void*)p; p += bytes; return r; };

  // 233 MiB total
  unsigned short* wA   = (unsigned short*)alloc((size_t)HPAD * DIM * 2);   // reused for every weight
  unsigned short* hn   = (unsigned short*)alloc((size_t)BATCH * DIM * 2);
  unsigned short* v    = (unsigned short*)alloc((size_t)BATCH * DIM * 2);
  float*          h2   = (float*)alloc((size_t)BATCH * DIM * 4);
  unsigned short* gbuf = (unsigned short*)alloc((size_t)BATCH * HPAD * 2); // u1 then g (in-place)
  unsigned short* cc   = hn;  // [BATCH, 2*DIM] bf16 overlays hn+v
  unsigned short* hn2  = hn;  // hn dead after GEMM1
  (void)v;

  const int SMEM = 131072;
  hipFuncSetAttribute(reinterpret_cast<const void*>(gemm256<1>),
                      hipFuncAttributeMaxDynamicSharedMemorySize, SMEM);
  hipFuncSetAttribute(reinterpret_cast<const void*>(gemm256<3>),
                      hipFuncAttributeMaxDynamicSharedMemorySize, SMEM);
  hipFuncSetAttribute(reinterpret_cast<const void*>(gemm256<4>),
                      hipFuncAttributeMaxDynamicSharedMemorySize, SMEM);
  hipFuncSetAttribute(reinterpret_cast<const void*>(gemm256<5>),
                      hipFuncAttributeMaxDynamicSharedMemorySize, SMEM);
  hipFuncSetAttribute(reinterpret_cast<const void*>(gemm256<6>),
                      hipFuncAttributeMaxDynamicSharedMemorySize, SMEM);

  const dim3 blk(512);
  const int t4_dd = DIM * DIM / 4;
  const int t4_hd = HPAD * DIM / 4;
  const int t4_dh = DIM * HPAD / 4;
  const int t4_dg = DIM * 2 * DIM / 4;

  // hn = rmsnorm((x+state)*0.7071, g1)
  norm_kernel<true><<<BATCH, 256, 0, stream>>>(x, st, g1, hn);

  // v = hn @ Wv^T + b_v          (Wv = rows [2*DIM, 3*DIM) of in_proj_w)
  convert_pad<<<(t4_dd + 255) / 256, 256, 0, stream>>>(ipw + (size_t)2 * DIM * DIM, wA, DIM, DIM, DIM, t4_dd);
  gemm256<1><<<dim3(32 * (DIM / 256)), blk, SMEM, stream>>>(hn, wA, DIM, DIM, ipb + 2 * DIM,
      nullptr, nullptr, nullptr, nullptr, v, DIM);

  // h2 = (x+state)*0.7071 + (v @ Wo^T + b_o)
  convert_pad<<<(t4_dd + 255) / 256, 256, 0, stream>>>(opw, wA, DIM, DIM, DIM, t4_dd);
  gemm256<3><<<dim3(32 * (DIM / 256)), blk, SMEM, stream>>>(v, wA, DIM, DIM, opb,
      x, st, nullptr, h2, nullptr, 0);

  // hn2 = rmsnorm(h2, g2)
  norm_kernel<false><<<BATCH, 256, 0, stream>>>(h2, nullptr, g2, hn2);

  // u1 = hn2 @ w1^T   (into gbuf, HPAD-padded)
  convert_pad<<<(t4_hd + 255) / 256, 256, 0, stream>>>(w1, wA, HSRC, DIM, DIM, t4_hd);
  gemm256<1><<<dim3(32 * (HPAD / 256)), blk, SMEM, stream>>>(hn2, wA, HPAD, DIM, nullptr,
      nullptr, nullptr, nullptr, nullptr, gbuf, HPAD);

  // g = silu(u1) * (hn2 @ w2^T)   (in-place on gbuf)
  convert_pad<<<(t4_hd + 255) / 256, 256, 0, stream>>>(w2, wA, HSRC, DIM, DIM, t4_hd);
  gemm256<4><<<dim3(32 * (HPAD / 256)), blk, SMEM, stream>>>(hn2, wA, HPAD, DIM, nullptr,
      nullptr, nullptr, gbuf, nullptr, gbuf, HPAD);

  // concat upper half: cc[:, DIM:2*DIM] = bf16(state)   (hn/v dead now)
  state_to_cc<<<(BATCH * DIM / 4) / 256, 256, 0, stream>>>(st, cc);

  // cand = h2 + g @ w3^T  ->  cc[:, 0:DIM] = bf16(cand)
  convert_pad<<<(t4_dh + 255) / 256, 256, 0, stream>>>(w3, wA, DIM, HSRC, HPAD, t4_dh);
  gemm256<5><<<dim3(32 * (DIM / 256)), blk, SMEM, stream>>>(gbuf, wA, DIM, HPAD, nullptr,
      h2, nullptr, nullptr, nullptr, cc, 2 * DIM);

  // out = z*cand + (1-z)*state,  z = sigmoid(cc @ gate_w^T + gate_b)
  convert_pad<<<(t4_dg + 255) / 256, 256, 0, stream>>>(gw, wA, DIM, 2 * DIM, 2 * DIM, t4_dg);
  gemm256<6><<<dim3(32 * (DIM / 256)), blk, SMEM, stream>>>(cc, wA, DIM, 2 * DIM, gb,
      nullptr, st, cc, (float*)d_out, nullptr, 2 * DIM);
}